// Round 5
// baseline (64.962 us; speedup 1.0000x reference)
//
#include <hip/hip_runtime.h>
#include <hip/hip_bf16.h>
#include <cstdint>
#include <cstddef>

#define KSZ 5
#define KK 25
#define EMB 64
#define CC 128
#define FILTERS 128

typedef __attribute__((ext_vector_type(8))) short short8;
typedef __attribute__((ext_vector_type(4))) float floatx4;

__device__ inline unsigned short f32_to_bf16(float f) {
    union { float f; unsigned u; } v; v.f = f;
    unsigned u = v.u;
    unsigned r = u + 0x7FFF + ((u >> 16) & 1);
    return (unsigned short)(r >> 16);
}

// ---------------- all weight transposes (f32 -> bf16, [K][N] -> [N][K]) ----------------
__global__ void wtrans_all_kernel(const float* __restrict__ w_sfine,
                                  const float* __restrict__ w_scoarse,
                                  const float* __restrict__ w_content,
                                  const float* __restrict__ w_coarse,
                                  const float* __restrict__ w_fineout,
                                  unsigned short* __restrict__ wsfT,
                                  unsigned short* __restrict__ wscT,
                                  unsigned short* __restrict__ wconT,
                                  unsigned short* __restrict__ wcT,
                                  unsigned short* __restrict__ wfT) {
    int i = blockIdx.x * blockDim.x + threadIdx.x;
    if (i < 8192) {
        int n = i >> 7, k = i & 127;
        wsfT[i] = f32_to_bf16(w_sfine[k * 64 + n]);
    } else if (i < 16384) {
        int j = i - 8192;
        int n = j >> 7, k = j & 127;
        wscT[j] = f32_to_bf16(w_scoarse[k * 64 + n]);
    } else if (i < 34816) {
        int j = i - 16384;
        int n = j / 576, k = j - n * 576;
        float v = (n < 25) ? w_content[k * 25 + n] : 0.0f;
        wconT[j] = f32_to_bf16(v);
    } else if (i < 51200) {
        int j = i - 34816;
        int o = j >> 7, k = j & 127;
        wcT[j] = f32_to_bf16(w_coarse[k * 128 + o]);
    } else if (i < 67584) {
        int j = i - 51200;
        int o = j >> 7, k = j & 127;
        wfT[j] = f32_to_bf16(w_fineout[k * 128 + o]);
    }
}

// ---------------- embed MFMA, LDS-free (both inputs in one grid) ----------------
// M=64 rows per block, 4 waves (wave = 16 rows x 64 cols). A loaded straight
// from global f32 and converted in-register; B from bf16 wT via uint4.
__global__ __launch_bounds__(256) void embed_both_kernel(
        const float* __restrict__ xf, const unsigned short* __restrict__ wTf,
        const float* __restrict__ xc, const unsigned short* __restrict__ wTc,
        const float* __restrict__ bias_c,
        unsigned short* __restrict__ yf, unsigned short* __restrict__ yc,
        int nf) {
    bool is_f = (int)blockIdx.x < nf;
    int blk = is_f ? blockIdx.x : (blockIdx.x - nf);
    const float* x = is_f ? xf : xc;
    const unsigned short* wT = is_f ? wTf : wTc;
    const float* bias = is_f ? nullptr : bias_c;
    unsigned short* y = is_f ? yf : yc;

    int tid = threadIdx.x;
    int wid = tid >> 6, lane = tid & 63;
    int lr = lane & 15, hi = lane >> 4, lk = hi * 8;

    size_t row0 = (size_t)blk * 64;
    int arow = wid * 16 + lr;
    const float* xr = x + (row0 + arow) * 128;

    floatx4 acc[4];
    #pragma unroll
    for (int ni = 0; ni < 4; ++ni)
        acc[ni] = (floatx4){0.f, 0.f, 0.f, 0.f};

    #pragma unroll
    for (int kk = 0; kk < 4; ++kk) {
        float4 a0 = *(const float4*)(xr + kk * 32 + lk);
        float4 a1 = *(const float4*)(xr + kk * 32 + lk + 4);
        unsigned short ah[8];
        ah[0] = f32_to_bf16(a0.x); ah[1] = f32_to_bf16(a0.y);
        ah[2] = f32_to_bf16(a0.z); ah[3] = f32_to_bf16(a0.w);
        ah[4] = f32_to_bf16(a1.x); ah[5] = f32_to_bf16(a1.y);
        ah[6] = f32_to_bf16(a1.z); ah[7] = f32_to_bf16(a1.w);
        short8 a = *(const short8*)ah;
        #pragma unroll
        for (int ni = 0; ni < 4; ++ni) {
            short8 bb = *(const short8*)(wT + (size_t)(ni * 16 + lr) * 128 + kk * 32 + lk);
            acc[ni] = __builtin_amdgcn_mfma_f32_16x16x32_bf16(a, bb, acc[ni], 0, 0, 0);
        }
    }

    #pragma unroll
    for (int ni = 0; ni < 4; ++ni) {
        int col = ni * 16 + lr;
        float bs = bias ? bias[col] : 0.0f;
        #pragma unroll
        for (int j = 0; j < 4; ++j) {
            int row = wid * 16 + hi * 4 + j;
            y[(row0 + row) * EMB + col] = f32_to_bf16(acc[ni][j] + bs);
        }
    }
}

// ---------------- content conv MFMA (both resolutions in one grid) ----------------
#define SP 72
#define SB 584
__global__ __launch_bounds__(256) void content_both_kernel(
        const unsigned short* __restrict__ embf,
        const unsigned short* __restrict__ embc,
        const unsigned short* __restrict__ wT,   // bf16 [32][576]
        const float* __restrict__ bias,          // [25]
        float* __restrict__ yf, float* __restrict__ yc,
        int nf) {
    __shared__ unsigned short Es[6 * 34 * SP];
    __shared__ unsigned short Bs[32 * SB];
    int tid = threadIdx.x;
    bool is_f = (int)blockIdx.x < nf;
    int blk = is_f ? blockIdx.x : (blockIdx.x - nf);
    const unsigned short* emb = is_f ? embf : embc;
    float* y = is_f ? yf : yc;
    int HT = is_f ? 32 : 16;
    int WT = is_f ? 4 : 2;
    int Hh = is_f ? 128 : 64;
    int Ww = is_f ? 128 : 64;

    int bx = blk % WT;
    int t = blk / WT;
    int by = t % HT;
    int b = t / HT;

    for (int ci = tid; ci < 1632; ci += 256) {
        int pi = ci >> 3, e8 = ci & 7;
        int hy = pi / 34, hx = pi - hy * 34;
        int gy = by * 4 + hy - 1, gx = bx * 32 + hx - 1;
        uint4 v = {0u, 0u, 0u, 0u};
        if (gy >= 0 && gy < Hh && gx >= 0 && gx < Ww)
            v = *(const uint4*)(emb + (((size_t)(b * Hh + gy)) * Ww + gx) * EMB + e8 * 8);
        *(uint4*)(&Es[pi * SP + e8 * 8]) = v;
    }
    for (int ci = tid; ci < 2304; ci += 256) {
        int n = ci / 72, k8 = ci - n * 72;
        *(uint4*)(&Bs[n * SB + k8 * 8]) = *(const uint4*)(wT + n * 576 + k8 * 8);
    }
    __syncthreads();

    int wid = tid >> 6, lane = tid & 63;
    int lr = lane & 15, hi = lane >> 4, lk = hi * 8;

    floatx4 acc[2][2];
    #pragma unroll
    for (int mi = 0; mi < 2; ++mi)
        #pragma unroll
        for (int ni = 0; ni < 2; ++ni)
            acc[mi][ni] = (floatx4){0.f, 0.f, 0.f, 0.f};

    #pragma unroll
    for (int tap = 0; tap < 9; ++tap) {
        int dy = tap / 3, dx = tap - dy * 3;
        #pragma unroll
        for (int ks = 0; ks < 2; ++ks) {
            short8 a[2], bb[2];
            #pragma unroll
            for (int mi = 0; mi < 2; ++mi) {
                int p = wid * 32 + mi * 16 + lr;
                int r = p >> 5, c = p & 31;
                a[mi] = *(const short8*)(&Es[((r + dy) * 34 + (c + dx)) * SP + ks * 32 + lk]);
            }
            #pragma unroll
            for (int ni = 0; ni < 2; ++ni)
                bb[ni] = *(const short8*)(&Bs[(ni * 16 + lr) * SB + tap * 64 + ks * 32 + lk]);
            #pragma unroll
            for (int mi = 0; mi < 2; ++mi)
                #pragma unroll
                for (int ni = 0; ni < 2; ++ni)
                    acc[mi][ni] = __builtin_amdgcn_mfma_f32_16x16x32_bf16(a[mi], bb[ni], acc[mi][ni], 0, 0, 0);
        }
    }

    #pragma unroll
    for (int mi = 0; mi < 2; ++mi) {
        #pragma unroll
        for (int ni = 0; ni < 2; ++ni) {
            int n = ni * 16 + lr;
            if (n < KK) {
                float bs = bias[n];
                #pragma unroll
                for (int j = 0; j < 4; ++j) {
                    int p = wid * 32 + mi * 16 + hi * 4 + j;
                    int r = p >> 5, c = p & 31;
                    size_t gq = ((size_t)(b * Hh + by * 4 + r)) * Ww + bx * 32 + c;
                    y[gq * KK + n] = acc[mi][ni][j] + bs;
                }
            }
        }
    }
}

// ---------------- fused softmax + CARAFE + gate ----------------
__global__ __launch_bounds__(256) void carafe_gate_kernel(
        const float* __restrict__ coarse,  // [B,h,w,128]
        const float* __restrict__ f_conv,  // [B,H,W,25]
        const float* __restrict__ c_conv,  // [B,h,w,25]
        const float* __restrict__ w_gate,  // [128]
        const float* __restrict__ b_gate,  // [1]
        unsigned short* __restrict__ xout, // bf16 [B,H,W,128]
        float* __restrict__ g_gate,        // [B*h*w]
        int h, int w) {
    __shared__ float patch[KK * CC];   // flat faithful [pos*128+ch], 12.8 KB
    __shared__ float wsm[4 * 32];
    int cpix = blockIdx.x;
    int npix = h * w;
    int b = cpix / npix;
    int rem = cpix - b * npix;
    int cy = rem / w;
    int cx = rem - cy * w;
    int tid = threadIdx.x;

    for (int ci = tid; ci < 800; ci += 256) {
        int k = ci >> 5;
        int c4 = (ci & 31) << 2;
        int dy = (k * 205) >> 10;
        int dx = k - dy * 5;
        int py = cy + dy - 2, px = cx + dx - 2;
        float4 v = {0.f, 0.f, 0.f, 0.f};
        if (py >= 0 && py < h && px >= 0 && px < w)
            v = *(const float4*)(coarse + (((size_t)(b * h + py)) * w + px) * CC + c4);
        *(float4*)(&patch[ci << 2]) = v;
    }

    int wid = tid >> 6, lane = tid & 63;
    int fy = 2 * cy + (wid >> 1);
    int fx = 2 * cx + (wid & 1);
    int H2 = 2 * h, W2 = 2 * w;
    size_t fq = ((size_t)(b * H2 + fy)) * W2 + fx;
    {
        int k = lane & 31;
        float v = -1e30f;
        if (k < KK)
            v = f_conv[fq * KK + k] + c_conv[(size_t)cpix * KK + k];
        float m = v;
        #pragma unroll
        for (int mask = 16; mask > 0; mask >>= 1)
            m = fmaxf(m, __shfl_xor(m, mask, 32));
        float e = (k < KK) ? __expf(v - m) : 0.0f;
        float s = e;
        #pragma unroll
        for (int mask = 16; mask > 0; mask >>= 1)
            s += __shfl_xor(s, mask, 32);
        if (lane < 32)
            wsm[wid * 32 + k] = e / s;
    }
    __syncthreads();

    if (wid == 0) {
        float acc = patch[12 * CC + lane] * w_gate[lane]
                  + patch[12 * CC + lane + 64] * w_gate[lane + 64];
        #pragma unroll
        for (int off = 32; off > 0; off >>= 1)
            acc += __shfl_down(acc, off, 64);
        if (lane == 0) {
            float z = acc + b_gate[0];
            g_gate[cpix] = 1.0f / (1.0f + __expf(-z));
        }
    }

    float wreg[28];
    #pragma unroll
    for (int j4 = 0; j4 < 7; ++j4)
        *(float4*)(&wreg[j4 * 4]) = *(const float4*)(&wsm[wid * 32 + j4 * 4]);

    unsigned short* outp = xout + fq * CC;
    #pragma unroll
    for (int cp = 0; cp < 2; ++cp) {
        int c = lane + 64 * cp;
        const float* pp = patch + c * KK;
        float acc = 0.0f;
        #pragma unroll
        for (int j = 0; j < KK; ++j)
            acc += wreg[j] * pp[j];
        outp[c] = f32_to_bf16(acc);
    }
}

// ---------------- fused final (M=64 tiles, Wf register-prefetch) ----------------
#define LDSP 136
__global__ __launch_bounds__(256) void final_kernel(
        const unsigned short* __restrict__ X,    // bf16 [M,128]
        const unsigned short* __restrict__ WcT,  // bf16 [o][k]
        const unsigned short* __restrict__ WfT,  // bf16 [p][o]
        const float* __restrict__ b_coarse,
        const float* __restrict__ b_fineout,
        const float* __restrict__ gate,          // [B*h*w]
        float* __restrict__ out) {
    __shared__ unsigned short Xs[64 * LDSP];
    __shared__ unsigned short Ws[128 * LDSP];
    int tid = threadIdx.x;
    int row0 = blockIdx.x * 64;

    // prefetch WfT into registers (overlaps staging + GEMM1)
    uint4 wfreg[8];
    {
        const uint4* wfsrc = (const uint4*)WfT;
        #pragma unroll
        for (int t = 0; t < 8; ++t)
            wfreg[t] = wfsrc[tid + t * 256];
    }
    {
        const uint4* src = (const uint4*)(X + (size_t)row0 * 128);
        for (int ci = tid; ci < 1024; ci += 256) {
            int r = ci >> 4, c = ci & 15;
            *(uint4*)(&Xs[r * LDSP + c * 8]) = src[ci];
        }
        const uint4* wsrc = (const uint4*)WcT;
        for (int ci = tid; ci < 2048; ci += 256) {
            int r = ci >> 4, c = ci & 15;
            *(uint4*)(&Ws[r * LDSP + c * 8]) = wsrc[ci];
        }
    }
    __syncthreads();

    int wid = tid >> 6, lane = tid & 63;
    int wm = wid >> 1, wn = wid & 1;
    int lr = lane & 15;
    int lk = (lane >> 4) * 8;
    int lrow4 = (lane >> 4) * 4;

    floatx4 acc1[2][4];
    #pragma unroll
    for (int mi = 0; mi < 2; ++mi)
        #pragma unroll
        for (int ni = 0; ni < 4; ++ni)
            acc1[mi][ni] = (floatx4){0.f, 0.f, 0.f, 0.f};

    #pragma unroll
    for (int kk = 0; kk < 128; kk += 32) {
        short8 a[2], bb[4];
        #pragma unroll
        for (int mi = 0; mi < 2; ++mi)
            a[mi] = *(const short8*)(&Xs[(wm * 32 + mi * 16 + lr) * LDSP + kk + lk]);
        #pragma unroll
        for (int ni = 0; ni < 4; ++ni)
            bb[ni] = *(const short8*)(&Ws[(wn * 64 + ni * 16 + lr) * LDSP + kk + lk]);
        #pragma unroll
        for (int mi = 0; mi < 2; ++mi)
            #pragma unroll
            for (int ni = 0; ni < 4; ++ni)
                acc1[mi][ni] = __builtin_amdgcn_mfma_f32_16x16x32_bf16(a[mi], bb[ni], acc1[mi][ni], 0, 0, 0);
    }
    __syncthreads();   // GEMM1 done reading Ws

    {
        #pragma unroll
        for (int t = 0; t < 8; ++t) {
            int ci = tid + t * 256;
            int r = ci >> 4, c = ci & 15;
            *(uint4*)(&Ws[r * LDSP + c * 8]) = wfreg[t];
        }
    }
    #pragma unroll
    for (int mi = 0; mi < 2; ++mi) {
        #pragma unroll
        for (int ni = 0; ni < 4; ++ni) {
            int col = wn * 64 + ni * 16 + lr;
            float bc = b_coarse[col];
            #pragma unroll
            for (int j = 0; j < 4; ++j) {
                int row = wm * 32 + mi * 16 + lrow4 + j;
                float v = acc1[mi][ni][j] + bc;
                acc1[mi][ni][j] = v;
                Xs[row * LDSP + col] = f32_to_bf16(v);
            }
        }
    }
    __syncthreads();

    floatx4 acc2[2][4];
    #pragma unroll
    for (int mi = 0; mi < 2; ++mi)
        #pragma unroll
        for (int ni = 0; ni < 4; ++ni)
            acc2[mi][ni] = (floatx4){0.f, 0.f, 0.f, 0.f};

    #pragma unroll
    for (int kk = 0; kk < 128; kk += 32) {
        short8 a[2], bb[4];
        #pragma unroll
        for (int mi = 0; mi < 2; ++mi)
            a[mi] = *(const short8*)(&Xs[(wm * 32 + mi * 16 + lr) * LDSP + kk + lk]);
        #pragma unroll
        for (int ni = 0; ni < 4; ++ni)
            bb[ni] = *(const short8*)(&Ws[(wn * 64 + ni * 16 + lr) * LDSP + kk + lk]);
        #pragma unroll
        for (int mi = 0; mi < 2; ++mi)
            #pragma unroll
            for (int ni = 0; ni < 4; ++ni)
                acc2[mi][ni] = __builtin_amdgcn_mfma_f32_16x16x32_bf16(a[mi], bb[ni], acc2[mi][ni], 0, 0, 0);
    }

    #pragma unroll
    for (int mi = 0; mi < 2; ++mi) {
        #pragma unroll
        for (int ni = 0; ni < 4; ++ni) {
            int col = wn * 64 + ni * 16 + lr;
            float bf = b_fineout[col];
            #pragma unroll
            for (int j = 0; j < 4; ++j) {
                int row = wm * 32 + mi * 16 + lrow4 + j;
                int q = row0 + row;
                int b = q >> 14;
                int remq = q & 16383;
                int fy = remq >> 7, fx = remq & 127;
                float g = gate[(b << 12) + ((fy >> 1) << 6) + (fx >> 1)];
                float co = acc1[mi][ni][j];
                float fo = acc2[mi][ni][j] + bf;
                out[(size_t)q * FILTERS + col] = g * fo + (1.0f - g) * co;
            }
        }
    }
}

extern "C" void kernel_launch(void* const* d_in, const int* in_sizes, int n_in,
                              void* d_out, int out_size, void* d_ws, size_t ws_size,
                              hipStream_t stream) {
    const float* fine      = (const float*)d_in[0];
    const float* coarse    = (const float*)d_in[1];
    const float* w_gate    = (const float*)d_in[2];
    const float* b_gate    = (const float*)d_in[3];
    const float* w_sfine   = (const float*)d_in[4];
    const float* w_scoarse = (const float*)d_in[5];
    const float* b_scoarse = (const float*)d_in[6];
    const float* w_content = (const float*)d_in[7];
    const float* b_content = (const float*)d_in[8];
    const float* w_coarse  = (const float*)d_in[9];
    const float* b_coarse  = (const float*)d_in[10];
    const float* w_fineout = (const float*)d_in[11];
    const float* b_fineout = (const float*)d_in[12];
    float* out = (float*)d_out;

    const int B = 2, H = 128, W = 128, h = 64, w = 64;
    const int MF = B * H * W;   // 32768
    const int MC = B * h * w;   // 8192

    char* ws = (char*)d_ws;
    size_t off = 0;
    auto alloc = [&](size_t bytes) {
        void* p = ws + off;
        off = (off + bytes + 255) & ~(size_t)255;
        return p;
    };
    float* g_gate            = (float*)alloc((size_t)MC * 4);
    unsigned short* f_emb    = (unsigned short*)alloc((size_t)MF * EMB * 2);
    unsigned short* c_emb    = (unsigned short*)alloc((size_t)MC * EMB * 2);
    float* f_conv            = (float*)alloc((size_t)MF * KK * 4);
    float* c_conv            = (float*)alloc((size_t)MC * KK * 4);
    unsigned short* x_bf16   = (unsigned short*)alloc((size_t)MF * CC * 2);
    unsigned short* wsfT     = (unsigned short*)alloc(64 * 128 * 2);
    unsigned short* wscT     = (unsigned short*)alloc(64 * 128 * 2);
    unsigned short* wconT    = (unsigned short*)alloc(32 * 576 * 2);
    unsigned short* wcT      = (unsigned short*)alloc(128 * 128 * 2);
    unsigned short* wfT      = (unsigned short*)alloc(128 * 128 * 2);

    const int NEF = MF / 64;          // 512 fine embed blocks
    const int NEC = MC / 64;          // 128 coarse embed blocks
    const int NCF = B * (H / 4) * (W / 32);   // 256 fine content blocks
    const int NCC = B * (h / 4) * (w / 32);   // 64 coarse content blocks

    wtrans_all_kernel<<<264, 256, 0, stream>>>(w_sfine, w_scoarse, w_content, w_coarse, w_fineout,
                                               wsfT, wscT, wconT, wcT, wfT);
    embed_both_kernel<<<NEF + NEC, 256, 0, stream>>>(fine, wsfT, coarse, wscT, b_scoarse,
                                                     f_emb, c_emb, NEF);
    content_both_kernel<<<NCF + NCC, 256, 0, stream>>>(f_emb, c_emb, wconT, b_content,
                                                       f_conv, c_conv, NCF);
    carafe_gate_kernel<<<MC, 256, 0, stream>>>(coarse, f_conv, c_conv, w_gate, b_gate,
                                               x_bf16, g_gate, h, w);
    final_kernel<<<MF / 64, 256, 0, stream>>>(x_bf16, wcT, wfT, b_coarse, b_fineout, g_gate, out);
}

// Round 6
// 57.458 us; speedup vs baseline: 1.1306x; 1.1306x over previous
//
#include <hip/hip_runtime.h>
#include <hip/hip_bf16.h>
#include <cstdint>
#include <cstddef>

#define KSZ 5
#define KK 25
#define EMB 64
#define CC 128
#define FILTERS 128

typedef __attribute__((ext_vector_type(8))) short short8;
typedef __attribute__((ext_vector_type(4))) float floatx4;

__device__ inline unsigned short f32_to_bf16(float f) {
    union { float f; unsigned u; } v; v.f = f;
    unsigned u = v.u;
    unsigned r = u + 0x7FFF + ((u >> 16) & 1);
    return (unsigned short)(r >> 16);
}

// ---------------- all weight transposes (f32 -> bf16, [K][N] -> [N][K]) ----------------
__global__ void wtrans_all_kernel(const float* __restrict__ w_sfine,
                                  const float* __restrict__ w_scoarse,
                                  const float* __restrict__ w_content,
                                  const float* __restrict__ w_coarse,
                                  const float* __restrict__ w_fineout,
                                  unsigned short* __restrict__ wsfT,
                                  unsigned short* __restrict__ wscT,
                                  unsigned short* __restrict__ wconT,
                                  unsigned short* __restrict__ wcT,
                                  unsigned short* __restrict__ wfT) {
    int i = blockIdx.x * blockDim.x + threadIdx.x;
    if (i < 8192) {
        int n = i >> 7, k = i & 127;
        wsfT[i] = f32_to_bf16(w_sfine[k * 64 + n]);
    } else if (i < 16384) {
        int j = i - 8192;
        int n = j >> 7, k = j & 127;
        wscT[j] = f32_to_bf16(w_scoarse[k * 64 + n]);
    } else if (i < 34816) {
        int j = i - 16384;
        int n = j / 576, k = j - n * 576;
        float v = (n < 25) ? w_content[k * 25 + n] : 0.0f;
        wconT[j] = f32_to_bf16(v);
    } else if (i < 51200) {
        int j = i - 34816;
        int o = j >> 7, k = j & 127;
        wcT[j] = f32_to_bf16(w_coarse[k * 128 + o]);
    } else if (i < 67584) {
        int j = i - 51200;
        int o = j >> 7, k = j & 127;
        wfT[j] = f32_to_bf16(w_fineout[k * 128 + o]);
    }
}

// ---------------- embed MFMA (both inputs in one grid), round-4 proven version ----------------
#define XS_P 136
__global__ __launch_bounds__(256) void embed_both_kernel(
        const float* __restrict__ xf, const unsigned short* __restrict__ wTf,
        const float* __restrict__ xc, const unsigned short* __restrict__ wTc,
        const float* __restrict__ bias_c,
        unsigned short* __restrict__ yf, unsigned short* __restrict__ yc,
        int nf) {
    __shared__ unsigned short Xs[128 * XS_P];
    __shared__ unsigned short Ws[64 * XS_P];
    int tid = threadIdx.x;
    bool is_f = (int)blockIdx.x < nf;
    int blk = is_f ? blockIdx.x : (blockIdx.x - nf);
    const float* x = is_f ? xf : xc;
    const unsigned short* wT = is_f ? wTf : wTc;
    const float* bias = is_f ? nullptr : bias_c;
    unsigned short* y = is_f ? yf : yc;
    size_t row0 = (size_t)blk * 128;

    {
        const float4* src = (const float4*)(x + row0 * 128);
        for (int ci = tid; ci < 4096; ci += 256) {
            int r = ci >> 5, c4 = ci & 31;
            float4 v = src[ci];
            uint2 u;
            u.x = (unsigned)f32_to_bf16(v.x) | ((unsigned)f32_to_bf16(v.y) << 16);
            u.y = (unsigned)f32_to_bf16(v.z) | ((unsigned)f32_to_bf16(v.w) << 16);
            *(uint2*)(&Xs[r * XS_P + c4 * 4]) = u;
        }
        const uint4* wsrc = (const uint4*)wT;
        for (int ci = tid; ci < 1024; ci += 256) {
            int n = ci >> 4, k8 = ci & 15;
            *(uint4*)(&Ws[n * XS_P + k8 * 8]) = wsrc[ci];
        }
    }
    __syncthreads();

    int wid = tid >> 6, lane = tid & 63;
    int lr = lane & 15, hi = lane >> 4, lk = hi * 8;

    floatx4 acc[2][4];
    #pragma unroll
    for (int mi = 0; mi < 2; ++mi)
        #pragma unroll
        for (int ni = 0; ni < 4; ++ni)
            acc[mi][ni] = (floatx4){0.f, 0.f, 0.f, 0.f};

    #pragma unroll
    for (int kk = 0; kk < 128; kk += 32) {
        short8 a[2], bb[4];
        #pragma unroll
        for (int mi = 0; mi < 2; ++mi)
            a[mi] = *(const short8*)(&Xs[(wid * 32 + mi * 16 + lr) * XS_P + kk + lk]);
        #pragma unroll
        for (int ni = 0; ni < 4; ++ni)
            bb[ni] = *(const short8*)(&Ws[(ni * 16 + lr) * XS_P + kk + lk]);
        #pragma unroll
        for (int mi = 0; mi < 2; ++mi)
            #pragma unroll
            for (int ni = 0; ni < 4; ++ni)
                acc[mi][ni] = __builtin_amdgcn_mfma_f32_16x16x32_bf16(a[mi], bb[ni], acc[mi][ni], 0, 0, 0);
    }

    #pragma unroll
    for (int mi = 0; mi < 2; ++mi) {
        #pragma unroll
        for (int ni = 0; ni < 4; ++ni) {
            int col = ni * 16 + lr;
            float bs = bias ? bias[col] : 0.0f;
            #pragma unroll
            for (int j = 0; j < 4; ++j) {
                int row = wid * 32 + mi * 16 + hi * 4 + j;
                y[(row0 + row) * EMB + col] = f32_to_bf16(acc[mi][ni][j] + bs);
            }
        }
    }
}

// ---------------- content conv MFMA (both resolutions in one grid) ----------------
#define SP 72
#define SB 584
__global__ __launch_bounds__(256) void content_both_kernel(
        const unsigned short* __restrict__ embf,
        const unsigned short* __restrict__ embc,
        const unsigned short* __restrict__ wT,   // bf16 [32][576]
        const float* __restrict__ bias,          // [25]
        float* __restrict__ yf, float* __restrict__ yc,
        int nf) {
    __shared__ unsigned short Es[6 * 34 * SP];
    __shared__ unsigned short Bs[32 * SB];
    int tid = threadIdx.x;
    bool is_f = (int)blockIdx.x < nf;
    int blk = is_f ? blockIdx.x : (blockIdx.x - nf);
    const unsigned short* emb = is_f ? embf : embc;
    float* y = is_f ? yf : yc;
    int HT = is_f ? 32 : 16;
    int WT = is_f ? 4 : 2;
    int Hh = is_f ? 128 : 64;
    int Ww = is_f ? 128 : 64;

    int bx = blk % WT;
    int t = blk / WT;
    int by = t % HT;
    int b = t / HT;

    for (int ci = tid; ci < 1632; ci += 256) {
        int pi = ci >> 3, e8 = ci & 7;
        int hy = pi / 34, hx = pi - hy * 34;
        int gy = by * 4 + hy - 1, gx = bx * 32 + hx - 1;
        uint4 v = {0u, 0u, 0u, 0u};
        if (gy >= 0 && gy < Hh && gx >= 0 && gx < Ww)
            v = *(const uint4*)(emb + (((size_t)(b * Hh + gy)) * Ww + gx) * EMB + e8 * 8);
        *(uint4*)(&Es[pi * SP + e8 * 8]) = v;
    }
    for (int ci = tid; ci < 2304; ci += 256) {
        int n = ci / 72, k8 = ci - n * 72;
        *(uint4*)(&Bs[n * SB + k8 * 8]) = *(const uint4*)(wT + n * 576 + k8 * 8);
    }
    __syncthreads();

    int wid = tid >> 6, lane = tid & 63;
    int lr = lane & 15, hi = lane >> 4, lk = hi * 8;

    floatx4 acc[2][2];
    #pragma unroll
    for (int mi = 0; mi < 2; ++mi)
        #pragma unroll
        for (int ni = 0; ni < 2; ++ni)
            acc[mi][ni] = (floatx4){0.f, 0.f, 0.f, 0.f};

    #pragma unroll
    for (int tap = 0; tap < 9; ++tap) {
        int dy = tap / 3, dx = tap - dy * 3;
        #pragma unroll
        for (int ks = 0; ks < 2; ++ks) {
            short8 a[2], bb[2];
            #pragma unroll
            for (int mi = 0; mi < 2; ++mi) {
                int p = wid * 32 + mi * 16 + lr;
                int r = p >> 5, c = p & 31;
                a[mi] = *(const short8*)(&Es[((r + dy) * 34 + (c + dx)) * SP + ks * 32 + lk]);
            }
            #pragma unroll
            for (int ni = 0; ni < 2; ++ni)
                bb[ni] = *(const short8*)(&Bs[(ni * 16 + lr) * SB + tap * 64 + ks * 32 + lk]);
            #pragma unroll
            for (int mi = 0; mi < 2; ++mi)
                #pragma unroll
                for (int ni = 0; ni < 2; ++ni)
                    acc[mi][ni] = __builtin_amdgcn_mfma_f32_16x16x32_bf16(a[mi], bb[ni], acc[mi][ni], 0, 0, 0);
        }
    }

    #pragma unroll
    for (int mi = 0; mi < 2; ++mi) {
        #pragma unroll
        for (int ni = 0; ni < 2; ++ni) {
            int n = ni * 16 + lr;
            if (n < KK) {
                float bs = bias[n];
                #pragma unroll
                for (int j = 0; j < 4; ++j) {
                    int p = wid * 32 + mi * 16 + hi * 4 + j;
                    int r = p >> 5, c = p & 31;
                    size_t gq = ((size_t)(b * Hh + by * 4 + r)) * Ww + bx * 32 + c;
                    y[gq * KK + n] = acc[mi][ni][j] + bs;
                }
            }
        }
    }
}

// ---------------- fused softmax + CARAFE + gate (pixel-pair gather) ----------------
// one block per coarse pixel. Softmax: 4 waves = 4 fine pixels (unchanged).
// Gather: thread t owns channel c=t&127 and pixel pair ph=t>>7 — each patch
// element read once per pair instead of once per pixel (halves LDS reads).
__global__ __launch_bounds__(256) void carafe_gate_kernel(
        const float* __restrict__ coarse,  // [B,h,w,128]
        const float* __restrict__ f_conv,  // [B,H,W,25]
        const float* __restrict__ c_conv,  // [B,h,w,25]
        const float* __restrict__ w_gate,  // [128]
        const float* __restrict__ b_gate,  // [1]
        unsigned short* __restrict__ xout, // bf16 [B,H,W,128]
        float* __restrict__ g_gate,        // [B*h*w]
        int h, int w) {
    __shared__ float patch[KK * CC];   // flat faithful [pos*128+ch], 12.8 KB
    __shared__ float wsm[4 * 32];
    int cpix = blockIdx.x;
    int npix = h * w;
    int b = cpix / npix;
    int rem = cpix - b * npix;
    int cy = rem / w;
    int cx = rem - cy * w;
    int tid = threadIdx.x;

    // Phase A: stage patch as float4
    for (int ci = tid; ci < 800; ci += 256) {
        int k = ci >> 5;
        int c4 = (ci & 31) << 2;
        int dy = (k * 205) >> 10;
        int dx = k - dy * 5;
        int py = cy + dy - 2, px = cx + dx - 2;
        float4 v = {0.f, 0.f, 0.f, 0.f};
        if (py >= 0 && py < h && px >= 0 && px < w)
            v = *(const float4*)(coarse + (((size_t)(b * h + py)) * w + px) * CC + c4);
        *(float4*)(&patch[ci << 2]) = v;
    }

    // Phase B: wave-parallel softmax (wave wid = fine pixel wid)
    int wid = tid >> 6, lane = tid & 63;
    int H2 = 2 * h, W2 = 2 * w;
    {
        int fy = 2 * cy + (wid >> 1);
        int fx = 2 * cx + (wid & 1);
        size_t fq = ((size_t)(b * H2 + fy)) * W2 + fx;
        int k = lane & 31;
        float v = -1e30f;
        if (k < KK)
            v = f_conv[fq * KK + k] + c_conv[(size_t)cpix * KK + k];
        float m = v;
        #pragma unroll
        for (int mask = 16; mask > 0; mask >>= 1)
            m = fmaxf(m, __shfl_xor(m, mask, 32));
        float e = (k < KK) ? __expf(v - m) : 0.0f;
        float s = e;
        #pragma unroll
        for (int mask = 16; mask > 0; mask >>= 1)
            s += __shfl_xor(s, mask, 32);
        if (lane < 32)
            wsm[wid * 32 + k] = e / s;
    }
    __syncthreads();

    // gate from staged center pixel (tap 12) — identical f32 values as gate conv
    if (wid == 0) {
        float acc = patch[12 * CC + lane] * w_gate[lane]
                  + patch[12 * CC + lane + 64] * w_gate[lane + 64];
        #pragma unroll
        for (int off = 32; off > 0; off >>= 1)
            acc += __shfl_down(acc, off, 64);
        if (lane == 0) {
            float z = acc + b_gate[0];
            g_gate[cpix] = 1.0f / (1.0f + __expf(-z));
        }
    }

    // Phase C: pixel-pair gather. ph=0 -> fine pixels 0,1 (fy=2cy, fx=2cx+{0,1});
    // ph=1 -> pixels 2,3 (fy=2cy+1). Weights register-cached via broadcast b128.
    {
        int ph = tid >> 7;          // pixel pair
        int c = tid & 127;          // channel
        float w0[28], w1[28];
        #pragma unroll
        for (int j4 = 0; j4 < 7; ++j4) {
            *(float4*)(&w0[j4 * 4]) = *(const float4*)(&wsm[(2 * ph) * 32 + j4 * 4]);
            *(float4*)(&w1[j4 * 4]) = *(const float4*)(&wsm[(2 * ph + 1) * 32 + j4 * 4]);
        }
        const float* pp = patch + c * KK;   // contiguous 25 floats (faithful flat view)
        float acc0 = 0.0f, acc1 = 0.0f;
        #pragma unroll
        for (int j = 0; j < KK; ++j) {
            float pv = pp[j];
            acc0 += w0[j] * pv;
            acc1 += w1[j] * pv;
        }
        int fy = 2 * cy + ph;
        size_t fq0 = ((size_t)(b * H2 + fy)) * W2 + 2 * cx;
        xout[fq0 * CC + c] = f32_to_bf16(acc0);
        xout[(fq0 + 1) * CC + c] = f32_to_bf16(acc1);
    }
}

// ---------------- fused final (M=64 tiles), round-4 proven version ----------------
#define LDSP 136
__global__ __launch_bounds__(256) void final_kernel(
        const unsigned short* __restrict__ X,    // bf16 [M,128]
        const unsigned short* __restrict__ WcT,  // bf16 [o][k]
        const unsigned short* __restrict__ WfT,  // bf16 [p][o]
        const float* __restrict__ b_coarse,
        const float* __restrict__ b_fineout,
        const float* __restrict__ gate,          // [B*h*w]
        float* __restrict__ out) {
    __shared__ unsigned short Xs[64 * LDSP];
    __shared__ unsigned short Ws[128 * LDSP];
    int tid = threadIdx.x;
    int row0 = blockIdx.x * 64;

    {
        const uint4* src = (const uint4*)(X + (size_t)row0 * 128);
        for (int ci = tid; ci < 1024; ci += 256) {
            int r = ci >> 4, c = ci & 15;
            *(uint4*)(&Xs[r * LDSP + c * 8]) = src[ci];
        }
        const uint4* wsrc = (const uint4*)WcT;
        for (int ci = tid; ci < 2048; ci += 256) {
            int r = ci >> 4, c = ci & 15;
            *(uint4*)(&Ws[r * LDSP + c * 8]) = wsrc[ci];
        }
    }
    __syncthreads();

    int wid = tid >> 6, lane = tid & 63;
    int wm = wid >> 1, wn = wid & 1;
    int lr = lane & 15;
    int lk = (lane >> 4) * 8;
    int lrow4 = (lane >> 4) * 4;

    floatx4 acc1[2][4];
    #pragma unroll
    for (int mi = 0; mi < 2; ++mi)
        #pragma unroll
        for (int ni = 0; ni < 4; ++ni)
            acc1[mi][ni] = (floatx4){0.f, 0.f, 0.f, 0.f};

    #pragma unroll
    for (int kk = 0; kk < 128; kk += 32) {
        short8 a[2], bb[4];
        #pragma unroll
        for (int mi = 0; mi < 2; ++mi)
            a[mi] = *(const short8*)(&Xs[(wm * 32 + mi * 16 + lr) * LDSP + kk + lk]);
        #pragma unroll
        for (int ni = 0; ni < 4; ++ni)
            bb[ni] = *(const short8*)(&Ws[(wn * 64 + ni * 16 + lr) * LDSP + kk + lk]);
        #pragma unroll
        for (int mi = 0; mi < 2; ++mi)
            #pragma unroll
            for (int ni = 0; ni < 4; ++ni)
                acc1[mi][ni] = __builtin_amdgcn_mfma_f32_16x16x32_bf16(a[mi], bb[ni], acc1[mi][ni], 0, 0, 0);
    }
    __syncthreads();

    {
        const uint4* wsrc = (const uint4*)WfT;
        for (int ci = tid; ci < 2048; ci += 256) {
            int r = ci >> 4, c = ci & 15;
            *(uint4*)(&Ws[r * LDSP + c * 8]) = wsrc[ci];
        }
    }
    #pragma unroll
    for (int mi = 0; mi < 2; ++mi) {
        #pragma unroll
        for (int ni = 0; ni < 4; ++ni) {
            int col = wn * 64 + ni * 16 + lr;
            float bc = b_coarse[col];
            #pragma unroll
            for (int j = 0; j < 4; ++j) {
                int row = wm * 32 + mi * 16 + lrow4 + j;
                float v = acc1[mi][ni][j] + bc;
                acc1[mi][ni][j] = v;
                Xs[row * LDSP + col] = f32_to_bf16(v);
            }
        }
    }
    __syncthreads();

    floatx4 acc2[2][4];
    #pragma unroll
    for (int mi = 0; mi < 2; ++mi)
        #pragma unroll
        for (int ni = 0; ni < 4; ++ni)
            acc2[mi][ni] = (floatx4){0.f, 0.f, 0.f, 0.f};

    #pragma unroll
    for (int kk = 0; kk < 128; kk += 32) {
        short8 a[2], bb[4];
        #pragma unroll
        for (int mi = 0; mi < 2; ++mi)
            a[mi] = *(const short8*)(&Xs[(wm * 32 + mi * 16 + lr) * LDSP + kk + lk]);
        #pragma unroll
        for (int ni = 0; ni < 4; ++ni)
            bb[ni] = *(const short8*)(&Ws[(wn * 64 + ni * 16 + lr) * LDSP + kk + lk]);
        #pragma unroll
        for (int mi = 0; mi < 2; ++mi)
            #pragma unroll
            for (int ni = 0; ni < 4; ++ni)
                acc2[mi][ni] = __builtin_amdgcn_mfma_f32_16x16x32_bf16(a[mi], bb[ni], acc2[mi][ni], 0, 0, 0);
    }

    #pragma unroll
    for (int mi = 0; mi < 2; ++mi) {
        #pragma unroll
        for (int ni = 0; ni < 4; ++ni) {
            int col = wn * 64 + ni * 16 + lr;
            float bf = b_fineout[col];
            #pragma unroll
            for (int j = 0; j < 4; ++j) {
                int row = wm * 32 + mi * 16 + lrow4 + j;
                int q = row0 + row;
                int b = q >> 14;
                int remq = q & 16383;
                int fy = remq >> 7, fx = remq & 127;
                float g = gate[(b << 12) + ((fy >> 1) << 6) + (fx >> 1)];
                float co = acc1[mi][ni][j];
                float fo = acc2[mi][ni][j] + bf;
                out[(size_t)q * FILTERS + col] = g * fo + (1.0f - g) * co;
            }
        }
    }
}

extern "C" void kernel_launch(void* const* d_in, const int* in_sizes, int n_in,
                              void* d_out, int out_size, void* d_ws, size_t ws_size,
                              hipStream_t stream) {
    const float* fine      = (const float*)d_in[0];
    const float* coarse    = (const float*)d_in[1];
    const float* w_gate    = (const float*)d_in[2];
    const float* b_gate    = (const float*)d_in[3];
    const float* w_sfine   = (const float*)d_in[4];
    const float* w_scoarse = (const float*)d_in[5];
    const float* b_scoarse = (const float*)d_in[6];
    const float* w_content = (const float*)d_in[7];
    const float* b_content = (const float*)d_in[8];
    const float* w_coarse  = (const float*)d_in[9];
    const float* b_coarse  = (const float*)d_in[10];
    const float* w_fineout = (const float*)d_in[11];
    const float* b_fineout = (const float*)d_in[12];
    float* out = (float*)d_out;

    const int B = 2, H = 128, W = 128, h = 64, w = 64;
    const int MF = B * H * W;   // 32768
    const int MC = B * h * w;   // 8192

    char* ws = (char*)d_ws;
    size_t off = 0;
    auto alloc = [&](size_t bytes) {
        void* p = ws + off;
        off = (off + bytes + 255) & ~(size_t)255;
        return p;
    };
    float* g_gate            = (float*)alloc((size_t)MC * 4);
    unsigned short* f_emb    = (unsigned short*)alloc((size_t)MF * EMB * 2);
    unsigned short* c_emb    = (unsigned short*)alloc((size_t)MC * EMB * 2);
    float* f_conv            = (float*)alloc((size_t)MF * KK * 4);
    float* c_conv            = (float*)alloc((size_t)MC * KK * 4);
    unsigned short* x_bf16   = (unsigned short*)alloc((size_t)MF * CC * 2);
    unsigned short* wsfT     = (unsigned short*)alloc(64 * 128 * 2);
    unsigned short* wscT     = (unsigned short*)alloc(64 * 128 * 2);
    unsigned short* wconT    = (unsigned short*)alloc(32 * 576 * 2);
    unsigned short* wcT      = (unsigned short*)alloc(128 * 128 * 2);
    unsigned short* wfT      = (unsigned short*)alloc(128 * 128 * 2);

    const int NEF = MF / 128;         // 256 fine embed blocks
    const int NEC = MC / 128;         // 64 coarse embed blocks
    const int NCF = B * (H / 4) * (W / 32);   // 256 fine content blocks
    const int NCC = B * (h / 4) * (w / 32);   // 64 coarse content blocks

    wtrans_all_kernel<<<264, 256, 0, stream>>>(w_sfine, w_scoarse, w_content, w_coarse, w_fineout,
                                               wsfT, wscT, wconT, wcT, wfT);
    embed_both_kernel<<<NEF + NEC, 256, 0, stream>>>(fine, wsfT, coarse, wscT, b_scoarse,
                                                     f_emb, c_emb, NEF);
    content_both_kernel<<<NCF + NCC, 256, 0, stream>>>(f_emb, c_emb, wconT, b_content,
                                                       f_conv, c_conv, NCF);
    carafe_gate_kernel<<<MC, 256, 0, stream>>>(coarse, f_conv, c_conv, w_gate, b_gate,
                                               x_bf16, g_gate, h, w);
    final_kernel<<<MF / 64, 256, 0, stream>>>(x_bf16, wcT, wfT, b_coarse, b_fineout, g_gate, out);
}

// Round 8
// 54.048 us; speedup vs baseline: 1.2019x; 1.0631x over previous
//
#include <hip/hip_runtime.h>
#include <hip/hip_bf16.h>
#include <cstdint>
#include <cstddef>

#define KSZ 5
#define KK 25
#define EMB 64
#define CC 128
#define FILTERS 128

typedef __attribute__((ext_vector_type(8))) short short8;
typedef __attribute__((ext_vector_type(4))) float floatx4;

__device__ inline unsigned short f32_to_bf16(float f) {
    union { float f; unsigned u; } v; v.f = f;
    unsigned u = v.u;
    unsigned r = u + 0x7FFF + ((u >> 16) & 1);
    return (unsigned short)(r >> 16);
}

// ---------------- embed MFMA + inline weight transpose; tail blocks do the
// remaining weight transposes (wconT/wcT/wfT) for later kernels ----------------
#define XS_P 136
__global__ __launch_bounds__(256) void embed_both_kernel(
        const float* __restrict__ xf, const float* __restrict__ wsf,   // [128][64] f32
        const float* __restrict__ xc, const float* __restrict__ wsc,   // [128][64] f32
        const float* __restrict__ bias_c,
        unsigned short* __restrict__ yf, unsigned short* __restrict__ yc,
        int nf, int nemb,
        const float* __restrict__ w_content, const float* __restrict__ w_coarse,
        const float* __restrict__ w_fineout,
        unsigned short* __restrict__ wconT, unsigned short* __restrict__ wcT,
        unsigned short* __restrict__ wfT) {
    int tid = threadIdx.x;

    // ---- tail blocks: weight transposes for content/final kernels ----
    if ((int)blockIdx.x >= nemb) {
        int idx = (blockIdx.x - nemb) * 256 + tid;   // 0..51199
        if (idx < 18432) {
            int n = idx / 576, k = idx - n * 576;
            float v = (n < 25) ? w_content[k * 25 + n] : 0.0f;
            wconT[idx] = f32_to_bf16(v);
        } else if (idx < 34816) {
            int j = idx - 18432;
            int o = j >> 7, k = j & 127;
            wcT[j] = f32_to_bf16(w_coarse[k * 128 + o]);
        } else {
            int j = idx - 34816;
            int o = j >> 7, k = j & 127;
            wfT[j] = f32_to_bf16(w_fineout[k * 128 + o]);
        }
        return;
    }

    __shared__ unsigned short Xs[128 * XS_P];
    __shared__ unsigned short Ws[64 * XS_P];
    bool is_f = (int)blockIdx.x < nf;
    int blk = is_f ? blockIdx.x : (blockIdx.x - nf);
    const float* x = is_f ? xf : xc;
    const float* wsrcf = is_f ? wsf : wsc;
    const float* bias = is_f ? nullptr : bias_c;
    unsigned short* y = is_f ? yf : yc;
    size_t row0 = (size_t)blk * 128;

    {
        const float4* src = (const float4*)(x + row0 * 128);
        for (int ci = tid; ci < 4096; ci += 256) {
            int r = ci >> 5, c4 = ci & 31;
            float4 v = src[ci];
            uint2 u;
            u.x = (unsigned)f32_to_bf16(v.x) | ((unsigned)f32_to_bf16(v.y) << 16);
            u.y = (unsigned)f32_to_bf16(v.z) | ((unsigned)f32_to_bf16(v.w) << 16);
            *(uint2*)(&Xs[r * XS_P + c4 * 4]) = u;
        }
        // inline transpose of the f32 weight: Ws[n][k] = bf16(w[k*64+n])
        for (int ci = tid; ci < 2048; ci += 256) {
            int k = ci >> 4;            // 0..127
            int n4 = (ci & 15) * 4;     // 0,4,...,60
            float4 v = *(const float4*)(wsrcf + k * 64 + n4);
            Ws[(n4 + 0) * XS_P + k] = f32_to_bf16(v.x);
            Ws[(n4 + 1) * XS_P + k] = f32_to_bf16(v.y);
            Ws[(n4 + 2) * XS_P + k] = f32_to_bf16(v.z);
            Ws[(n4 + 3) * XS_P + k] = f32_to_bf16(v.w);
        }
    }
    __syncthreads();

    int wid = tid >> 6, lane = tid & 63;
    int lr = lane & 15, hi = lane >> 4, lk = hi * 8;

    floatx4 acc[2][4];
    #pragma unroll
    for (int mi = 0; mi < 2; ++mi)
        #pragma unroll
        for (int ni = 0; ni < 4; ++ni)
            acc[mi][ni] = (floatx4){0.f, 0.f, 0.f, 0.f};

    #pragma unroll
    for (int kk = 0; kk < 128; kk += 32) {
        short8 a[2], bb[4];
        #pragma unroll
        for (int mi = 0; mi < 2; ++mi)
            a[mi] = *(const short8*)(&Xs[(wid * 32 + mi * 16 + lr) * XS_P + kk + lk]);
        #pragma unroll
        for (int ni = 0; ni < 4; ++ni)
            bb[ni] = *(const short8*)(&Ws[(ni * 16 + lr) * XS_P + kk + lk]);
        #pragma unroll
        for (int mi = 0; mi < 2; ++mi)
            #pragma unroll
            for (int ni = 0; ni < 4; ++ni)
                acc[mi][ni] = __builtin_amdgcn_mfma_f32_16x16x32_bf16(a[mi], bb[ni], acc[mi][ni], 0, 0, 0);
    }

    #pragma unroll
    for (int mi = 0; mi < 2; ++mi) {
        #pragma unroll
        for (int ni = 0; ni < 4; ++ni) {
            int col = ni * 16 + lr;
            float bs = bias ? bias[col] : 0.0f;
            #pragma unroll
            for (int j = 0; j < 4; ++j) {
                int row = wid * 32 + mi * 16 + hi * 4 + j;
                y[(row0 + row) * EMB + col] = f32_to_bf16(acc[mi][ni][j] + bs);
            }
        }
    }
}

// ---------------- content conv MFMA (both resolutions in one grid) ----------------
#define SP 72
#define SB 584
__global__ __launch_bounds__(256) void content_both_kernel(
        const unsigned short* __restrict__ embf,
        const unsigned short* __restrict__ embc,
        const unsigned short* __restrict__ wT,   // bf16 [32][576]
        const float* __restrict__ bias,          // [25]
        float* __restrict__ yf, float* __restrict__ yc,
        int nf) {
    __shared__ unsigned short Es[6 * 34 * SP];
    __shared__ unsigned short Bs[32 * SB];
    int tid = threadIdx.x;
    bool is_f = (int)blockIdx.x < nf;
    int blk = is_f ? blockIdx.x : (blockIdx.x - nf);
    const unsigned short* emb = is_f ? embf : embc;
    float* y = is_f ? yf : yc;
    int HT = is_f ? 32 : 16;
    int WT = is_f ? 4 : 2;
    int Hh = is_f ? 128 : 64;
    int Ww = is_f ? 128 : 64;

    int bx = blk % WT;
    int t = blk / WT;
    int by = t % HT;
    int b = t / HT;

    for (int ci = tid; ci < 1632; ci += 256) {
        int pi = ci >> 3, e8 = ci & 7;
        int hy = pi / 34, hx = pi - hy * 34;
        int gy = by * 4 + hy - 1, gx = bx * 32 + hx - 1;
        uint4 v = {0u, 0u, 0u, 0u};
        if (gy >= 0 && gy < Hh && gx >= 0 && gx < Ww)
            v = *(const uint4*)(emb + (((size_t)(b * Hh + gy)) * Ww + gx) * EMB + e8 * 8);
        *(uint4*)(&Es[pi * SP + e8 * 8]) = v;
    }
    for (int ci = tid; ci < 2304; ci += 256) {
        int n = ci / 72, k8 = ci - n * 72;
        *(uint4*)(&Bs[n * SB + k8 * 8]) = *(const uint4*)(wT + n * 576 + k8 * 8);
    }
    __syncthreads();

    int wid = tid >> 6, lane = tid & 63;
    int lr = lane & 15, hi = lane >> 4, lk = hi * 8;

    floatx4 acc[2][2];
    #pragma unroll
    for (int mi = 0; mi < 2; ++mi)
        #pragma unroll
        for (int ni = 0; ni < 2; ++ni)
            acc[mi][ni] = (floatx4){0.f, 0.f, 0.f, 0.f};

    #pragma unroll
    for (int tap = 0; tap < 9; ++tap) {
        int dy = tap / 3, dx = tap - dy * 3;
        #pragma unroll
        for (int ks = 0; ks < 2; ++ks) {
            short8 a[2], bb[2];
            #pragma unroll
            for (int mi = 0; mi < 2; ++mi) {
                int p = wid * 32 + mi * 16 + lr;
                int r = p >> 5, c = p & 31;
                a[mi] = *(const short8*)(&Es[((r + dy) * 34 + (c + dx)) * SP + ks * 32 + lk]);
            }
            #pragma unroll
            for (int ni = 0; ni < 2; ++ni)
                bb[ni] = *(const short8*)(&Bs[(ni * 16 + lr) * SB + tap * 64 + ks * 32 + lk]);
            #pragma unroll
            for (int mi = 0; mi < 2; ++mi)
                #pragma unroll
                for (int ni = 0; ni < 2; ++ni)
                    acc[mi][ni] = __builtin_amdgcn_mfma_f32_16x16x32_bf16(a[mi], bb[ni], acc[mi][ni], 0, 0, 0);
        }
    }

    #pragma unroll
    for (int mi = 0; mi < 2; ++mi) {
        #pragma unroll
        for (int ni = 0; ni < 2; ++ni) {
            int n = ni * 16 + lr;
            if (n < KK) {
                float bs = bias[n];
                #pragma unroll
                for (int j = 0; j < 4; ++j) {
                    int p = wid * 32 + mi * 16 + hi * 4 + j;
                    int r = p >> 5, c = p & 31;
                    size_t gq = ((size_t)(b * Hh + by * 4 + r)) * Ww + bx * 32 + c;
                    y[gq * KK + n] = acc[mi][ni][j] + bs;
                }
            }
        }
    }
}

// ---------------- fused softmax + CARAFE + gate (pixel-pair gather) ----------------
__global__ __launch_bounds__(256) void carafe_gate_kernel(
        const float* __restrict__ coarse,  // [B,h,w,128]
        const float* __restrict__ f_conv,  // [B,H,W,25]
        const float* __restrict__ c_conv,  // [B,h,w,25]
        const float* __restrict__ w_gate,  // [128]
        const float* __restrict__ b_gate,  // [1]
        unsigned short* __restrict__ xout, // bf16 [B,H,W,128]
        float* __restrict__ g_gate,        // [B*h*w]
        int h, int w) {
    __shared__ float patch[KK * CC];   // flat faithful [pos*128+ch], 12.8 KB
    __shared__ float wsm[4 * 32];
    int cpix = blockIdx.x;
    int npix = h * w;
    int b = cpix / npix;
    int rem = cpix - b * npix;
    int cy = rem / w;
    int cx = rem - cy * w;
    int tid = threadIdx.x;

    // Phase A: stage patch as float4
    for (int ci = tid; ci < 800; ci += 256) {
        int k = ci >> 5;
        int c4 = (ci & 31) << 2;
        int dy = (k * 205) >> 10;
        int dx = k - dy * 5;
        int py = cy + dy - 2, px = cx + dx - 2;
        float4 v = {0.f, 0.f, 0.f, 0.f};
        if (py >= 0 && py < h && px >= 0 && px < w)
            v = *(const float4*)(coarse + (((size_t)(b * h + py)) * w + px) * CC + c4);
        *(float4*)(&patch[ci << 2]) = v;
    }

    // Phase B: wave-parallel softmax (wave wid = fine pixel wid)
    int wid = tid >> 6, lane = tid & 63;
    int H2 = 2 * h, W2 = 2 * w;
    {
        int fy = 2 * cy + (wid >> 1);
        int fx = 2 * cx + (wid & 1);
        size_t fq = ((size_t)(b * H2 + fy)) * W2 + fx;
        int k = lane & 31;
        float v = -1e30f;
        if (k < KK)
            v = f_conv[fq * KK + k] + c_conv[(size_t)cpix * KK + k];
        float m = v;
        #pragma unroll
        for (int mask = 16; mask > 0; mask >>= 1)
            m = fmaxf(m, __shfl_xor(m, mask, 32));
        float e = (k < KK) ? __expf(v - m) : 0.0f;
        float s = e;
        #pragma unroll
        for (int mask = 16; mask > 0; mask >>= 1)
            s += __shfl_xor(s, mask, 32);
        if (lane < 32)
            wsm[wid * 32 + k] = e / s;
    }
    __syncthreads();

    // gate from staged center pixel (tap 12) — identical f32 values as gate conv
    if (wid == 0) {
        float acc = patch[12 * CC + lane] * w_gate[lane]
                  + patch[12 * CC + lane + 64] * w_gate[lane + 64];
        #pragma unroll
        for (int off = 32; off > 0; off >>= 1)
            acc += __shfl_down(acc, off, 64);
        if (lane == 0) {
            float z = acc + b_gate[0];
            g_gate[cpix] = 1.0f / (1.0f + __expf(-z));
        }
    }

    // Phase C: pixel-pair gather
    {
        int ph = tid >> 7;          // pixel pair
        int c = tid & 127;          // channel
        float w0[28], w1[28];
        #pragma unroll
        for (int j4 = 0; j4 < 7; ++j4) {
            *(float4*)(&w0[j4 * 4]) = *(const float4*)(&wsm[(2 * ph) * 32 + j4 * 4]);
            *(float4*)(&w1[j4 * 4]) = *(const float4*)(&wsm[(2 * ph + 1) * 32 + j4 * 4]);
        }
        const float* pp = patch + c * KK;   // contiguous 25 floats (faithful flat view)
        float acc0 = 0.0f, acc1 = 0.0f;
        #pragma unroll
        for (int j = 0; j < KK; ++j) {
            float pv = pp[j];
            acc0 += w0[j] * pv;
            acc1 += w1[j] * pv;
        }
        int fy = 2 * cy + ph;
        size_t fq0 = ((size_t)(b * H2 + fy)) * W2 + 2 * cx;
        xout[fq0 * CC + c] = f32_to_bf16(acc0);
        xout[(fq0 + 1) * CC + c] = f32_to_bf16(acc1);
    }
}

// ---------------- fused final (M=64 tiles), proven version ----------------
#define LDSP 136
__global__ __launch_bounds__(256) void final_kernel(
        const unsigned short* __restrict__ X,    // bf16 [M,128]
        const unsigned short* __restrict__ WcT,  // bf16 [o][k]
        const unsigned short* __restrict__ WfT,  // bf16 [p][o]
        const float* __restrict__ b_coarse,
        const float* __restrict__ b_fineout,
        const float* __restrict__ gate,          // [B*h*w]
        float* __restrict__ out) {
    __shared__ unsigned short Xs[64 * LDSP];
    __shared__ unsigned short Ws[128 * LDSP];
    int tid = threadIdx.x;
    int row0 = blockIdx.x * 64;

    {
        const uint4* src = (const uint4*)(X + (size_t)row0 * 128);
        for (int ci = tid; ci < 1024; ci += 256) {
            int r = ci >> 4, c = ci & 15;
            *(uint4*)(&Xs[r * LDSP + c * 8]) = src[ci];
        }
        const uint4* wsrc = (const uint4*)WcT;
        for (int ci = tid; ci < 2048; ci += 256) {
            int r = ci >> 4, c = ci & 15;
            *(uint4*)(&Ws[r * LDSP + c * 8]) = wsrc[ci];
        }
    }
    __syncthreads();

    int wid = tid >> 6, lane = tid & 63;
    int wm = wid >> 1, wn = wid & 1;
    int lr = lane & 15;
    int lk = (lane >> 4) * 8;
    int lrow4 = (lane >> 4) * 4;

    floatx4 acc1[2][4];
    #pragma unroll
    for (int mi = 0; mi < 2; ++mi)
        #pragma unroll
        for (int ni = 0; ni < 4; ++ni)
            acc1[mi][ni] = (floatx4){0.f, 0.f, 0.f, 0.f};

    #pragma unroll
    for (int kk = 0; kk < 128; kk += 32) {
        short8 a[2], bb[4];
        #pragma unroll
        for (int mi = 0; mi < 2; ++mi)
            a[mi] = *(const short8*)(&Xs[(wm * 32 + mi * 16 + lr) * LDSP + kk + lk]);
        #pragma unroll
        for (int ni = 0; ni < 4; ++ni)
            bb[ni] = *(const short8*)(&Ws[(wn * 64 + ni * 16 + lr) * LDSP + kk + lk]);
        #pragma unroll
        for (int mi = 0; mi < 2; ++mi)
            #pragma unroll
            for (int ni = 0; ni < 4; ++ni)
                acc1[mi][ni] = __builtin_amdgcn_mfma_f32_16x16x32_bf16(a[mi], bb[ni], acc1[mi][ni], 0, 0, 0);
    }
    __syncthreads();

    {
        const uint4* wsrc = (const uint4*)WfT;
        for (int ci = tid; ci < 2048; ci += 256) {
            int r = ci >> 4, c = ci & 15;
            *(uint4*)(&Ws[r * LDSP + c * 8]) = wsrc[ci];
        }
    }
    #pragma unroll
    for (int mi = 0; mi < 2; ++mi) {
        #pragma unroll
        for (int ni = 0; ni < 4; ++ni) {
            int col = wn * 64 + ni * 16 + lr;
            float bc = b_coarse[col];
            #pragma unroll
            for (int j = 0; j < 4; ++j) {
                int row = wm * 32 + mi * 16 + lrow4 + j;
                float v = acc1[mi][ni][j] + bc;
                acc1[mi][ni][j] = v;
                Xs[row * LDSP + col] = f32_to_bf16(v);
            }
        }
    }
    __syncthreads();

    floatx4 acc2[2][4];
    #pragma unroll
    for (int mi = 0; mi < 2; ++mi)
        #pragma unroll
        for (int ni = 0; ni < 4; ++ni)
            acc2[mi][ni] = (floatx4){0.f, 0.f, 0.f, 0.f};

    #pragma unroll
    for (int kk = 0; kk < 128; kk += 32) {
        short8 a[2], bb[4];
        #pragma unroll
        for (int mi = 0; mi < 2; ++mi)
            a[mi] = *(const short8*)(&Xs[(wm * 32 + mi * 16 + lr) * LDSP + kk + lk]);
        #pragma unroll
        for (int ni = 0; ni < 4; ++ni)
            bb[ni] = *(const short8*)(&Ws[(wn * 64 + ni * 16 + lr) * LDSP + kk + lk]);
        #pragma unroll
        for (int mi = 0; mi < 2; ++mi)
            #pragma unroll
            for (int ni = 0; ni < 4; ++ni)
                acc2[mi][ni] = __builtin_amdgcn_mfma_f32_16x16x32_bf16(a[mi], bb[ni], acc2[mi][ni], 0, 0, 0);
    }

    #pragma unroll
    for (int mi = 0; mi < 2; ++mi) {
        #pragma unroll
        for (int ni = 0; ni < 4; ++ni) {
            int col = wn * 64 + ni * 16 + lr;
            float bf = b_fineout[col];
            #pragma unroll
            for (int j = 0; j < 4; ++j) {
                int row = wm * 32 + mi * 16 + lrow4 + j;
                int q = row0 + row;
                int b = q >> 14;
                int remq = q & 16383;
                int fy = remq >> 7, fx = remq & 127;
                float g = gate[(b << 12) + ((fy >> 1) << 6) + (fx >> 1)];
                float co = acc1[mi][ni][j];
                float fo = acc2[mi][ni][j] + bf;
                out[(size_t)q * FILTERS + col] = g * fo + (1.0f - g) * co;
            }
        }
    }
}

extern "C" void kernel_launch(void* const* d_in, const int* in_sizes, int n_in,
                              void* d_out, int out_size, void* d_ws, size_t ws_size,
                              hipStream_t stream) {
    const float* fine      = (const float*)d_in[0];
    const float* coarse    = (const float*)d_in[1];
    const float* w_gate    = (const float*)d_in[2];
    const float* b_gate    = (const float*)d_in[3];
    const float* w_sfine   = (const float*)d_in[4];
    const float* w_scoarse = (const float*)d_in[5];
    const float* b_scoarse = (const float*)d_in[6];
    const float* w_content = (const float*)d_in[7];
    const float* b_content = (const float*)d_in[8];
    const float* w_coarse  = (const float*)d_in[9];
    const float* b_coarse  = (const float*)d_in[10];
    const float* w_fineout = (const float*)d_in[11];
    const float* b_fineout = (const float*)d_in[12];
    float* out = (float*)d_out;

    const int B = 2, H = 128, W = 128, h = 64, w = 64;
    const int MF = B * H * W;   // 32768
    const int MC = B * h * w;   // 8192

    char* ws = (char*)d_ws;
    size_t off = 0;
    auto alloc = [&](size_t bytes) {
        void* p = ws + off;
        off = (off + bytes + 255) & ~(size_t)255;
        return p;
    };
    float* g_gate            = (float*)alloc((size_t)MC * 4);
    unsigned short* f_emb    = (unsigned short*)alloc((size_t)MF * EMB * 2);
    unsigned short* c_emb    = (unsigned short*)alloc((size_t)MC * EMB * 2);
    float* f_conv            = (float*)alloc((size_t)MF * KK * 4);
    float* c_conv            = (float*)alloc((size_t)MC * KK * 4);
    unsigned short* x_bf16   = (unsigned short*)alloc((size_t)MF * CC * 2);
    unsigned short* wconT    = (unsigned short*)alloc(32 * 576 * 2);
    unsigned short* wcT      = (unsigned short*)alloc(128 * 128 * 2);
    unsigned short* wfT      = (unsigned short*)alloc(128 * 128 * 2);

    const int NEF = MF / 128;         // 256 fine embed blocks
    const int NEC = MC / 128;         // 64 coarse embed blocks
    const int NEB = NEF + NEC;        // 320 embed blocks
    const int NWT = 200;              // 51200 transpose elems / 256
    const int NCF = B * (H / 4) * (W / 32);   // 256 fine content blocks
    const int NCC = B * (h / 4) * (w / 32);   // 64 coarse content blocks

    embed_both_kernel<<<NEB + NWT, 256, 0, stream>>>(fine, w_sfine, coarse, w_scoarse, b_scoarse,
                                                     f_emb, c_emb, NEF, NEB,
                                                     w_content, w_coarse, w_fineout,
                                                     wconT, wcT, wfT);
    content_both_kernel<<<NCF + NCC, 256, 0, stream>>>(f_emb, c_emb, wconT, b_content,
                                                       f_conv, c_conv, NCF);
    carafe_gate_kernel<<<MC, 256, 0, stream>>>(coarse, f_conv, c_conv, w_gate, b_gate,
                                               x_bf16, g_gate, h, w);
    final_kernel<<<MF / 64, 256, 0, stream>>>(x_bf16, wcT, wfT, b_coarse, b_fineout, g_gate, out);
}

// Round 9
// 49.997 us; speedup vs baseline: 1.2993x; 1.0810x over previous
//
#include <hip/hip_runtime.h>
#include <hip/hip_bf16.h>
#include <cstdint>
#include <cstddef>

#define KSZ 5
#define KK 25
#define EMB 64
#define CC 128
#define FILTERS 128

typedef __attribute__((ext_vector_type(8))) short short8;
typedef __attribute__((ext_vector_type(4))) float floatx4;

__device__ inline unsigned short f32_to_bf16(float f) {
    union { float f; unsigned u; } v; v.f = f;
    unsigned u = v.u;
    unsigned r = u + 0x7FFF + ((u >> 16) & 1);
    return (unsigned short)(r >> 16);
}

// ---------------- embed MFMA + inline weight transpose; tail blocks do the
// remaining weight transposes (wconT/wcT/wfT) for later kernels ----------------
#define XS_P 136
__global__ __launch_bounds__(256) void embed_both_kernel(
        const float* __restrict__ xf, const float* __restrict__ wsf,   // [128][64] f32
        const float* __restrict__ xc, const float* __restrict__ wsc,   // [128][64] f32
        const float* __restrict__ bias_c,
        unsigned short* __restrict__ yf, unsigned short* __restrict__ yc,
        int nf, int nemb,
        const float* __restrict__ w_content, const float* __restrict__ w_coarse,
        const float* __restrict__ w_fineout,
        unsigned short* __restrict__ wconT, unsigned short* __restrict__ wcT,
        unsigned short* __restrict__ wfT) {
    int tid = threadIdx.x;

    // ---- tail blocks: weight transposes for content/final kernels ----
    if ((int)blockIdx.x >= nemb) {
        int idx = (blockIdx.x - nemb) * 256 + tid;   // 0..51199
        if (idx < 18432) {
            int n = idx / 576, k = idx - n * 576;
            float v = (n < 25) ? w_content[k * 25 + n] : 0.0f;
            wconT[idx] = f32_to_bf16(v);
        } else if (idx < 34816) {
            int j = idx - 18432;
            int o = j >> 7, k = j & 127;
            wcT[j] = f32_to_bf16(w_coarse[k * 128 + o]);
        } else {
            int j = idx - 34816;
            int o = j >> 7, k = j & 127;
            wfT[j] = f32_to_bf16(w_fineout[k * 128 + o]);
        }
        return;
    }

    __shared__ unsigned short Xs[128 * XS_P];
    __shared__ unsigned short Ws[64 * XS_P];
    bool is_f = (int)blockIdx.x < nf;
    int blk = is_f ? blockIdx.x : (blockIdx.x - nf);
    const float* x = is_f ? xf : xc;
    const float* wsrcf = is_f ? wsf : wsc;
    const float* bias = is_f ? nullptr : bias_c;
    unsigned short* y = is_f ? yf : yc;
    size_t row0 = (size_t)blk * 128;

    {
        const float4* src = (const float4*)(x + row0 * 128);
        for (int ci = tid; ci < 4096; ci += 256) {
            int r = ci >> 5, c4 = ci & 31;
            float4 v = src[ci];
            uint2 u;
            u.x = (unsigned)f32_to_bf16(v.x) | ((unsigned)f32_to_bf16(v.y) << 16);
            u.y = (unsigned)f32_to_bf16(v.z) | ((unsigned)f32_to_bf16(v.w) << 16);
            *(uint2*)(&Xs[r * XS_P + c4 * 4]) = u;
        }
        // inline transpose of the f32 weight: Ws[n][k] = bf16(w[k*64+n])
        for (int ci = tid; ci < 2048; ci += 256) {
            int k = ci >> 4;            // 0..127
            int n4 = (ci & 15) * 4;     // 0,4,...,60
            float4 v = *(const float4*)(wsrcf + k * 64 + n4);
            Ws[(n4 + 0) * XS_P + k] = f32_to_bf16(v.x);
            Ws[(n4 + 1) * XS_P + k] = f32_to_bf16(v.y);
            Ws[(n4 + 2) * XS_P + k] = f32_to_bf16(v.z);
            Ws[(n4 + 3) * XS_P + k] = f32_to_bf16(v.w);
        }
    }
    __syncthreads();

    int wid = tid >> 6, lane = tid & 63;
    int lr = lane & 15, hi = lane >> 4, lk = hi * 8;

    floatx4 acc[2][4];
    #pragma unroll
    for (int mi = 0; mi < 2; ++mi)
        #pragma unroll
        for (int ni = 0; ni < 4; ++ni)
            acc[mi][ni] = (floatx4){0.f, 0.f, 0.f, 0.f};

    #pragma unroll
    for (int kk = 0; kk < 128; kk += 32) {
        short8 a[2], bb[4];
        #pragma unroll
        for (int mi = 0; mi < 2; ++mi)
            a[mi] = *(const short8*)(&Xs[(wid * 32 + mi * 16 + lr) * XS_P + kk + lk]);
        #pragma unroll
        for (int ni = 0; ni < 4; ++ni)
            bb[ni] = *(const short8*)(&Ws[(ni * 16 + lr) * XS_P + kk + lk]);
        #pragma unroll
        for (int mi = 0; mi < 2; ++mi)
            #pragma unroll
            for (int ni = 0; ni < 4; ++ni)
                acc[mi][ni] = __builtin_amdgcn_mfma_f32_16x16x32_bf16(a[mi], bb[ni], acc[mi][ni], 0, 0, 0);
    }

    #pragma unroll
    for (int mi = 0; mi < 2; ++mi) {
        #pragma unroll
        for (int ni = 0; ni < 4; ++ni) {
            int col = ni * 16 + lr;
            float bs = bias ? bias[col] : 0.0f;
            #pragma unroll
            for (int j = 0; j < 4; ++j) {
                int row = wid * 32 + mi * 16 + hi * 4 + j;
                y[(row0 + row) * EMB + col] = f32_to_bf16(acc[mi][ni][j] + bs);
            }
        }
    }
}

// ---------------- content conv MFMA (both resolutions in one grid) ----------------
#define SP 72
#define SB 584
__global__ __launch_bounds__(256) void content_both_kernel(
        const unsigned short* __restrict__ embf,
        const unsigned short* __restrict__ embc,
        const unsigned short* __restrict__ wT,   // bf16 [32][576]
        const float* __restrict__ bias,          // [25]
        float* __restrict__ yf, float* __restrict__ yc,
        int nf) {
    __shared__ unsigned short Es[6 * 34 * SP];
    __shared__ unsigned short Bs[32 * SB];
    int tid = threadIdx.x;
    bool is_f = (int)blockIdx.x < nf;
    int blk = is_f ? blockIdx.x : (blockIdx.x - nf);
    const unsigned short* emb = is_f ? embf : embc;
    float* y = is_f ? yf : yc;
    int HT = is_f ? 32 : 16;
    int WT = is_f ? 4 : 2;
    int Hh = is_f ? 128 : 64;
    int Ww = is_f ? 128 : 64;

    int bx = blk % WT;
    int t = blk / WT;
    int by = t % HT;
    int b = t / HT;

    for (int ci = tid; ci < 1632; ci += 256) {
        int pi = ci >> 3, e8 = ci & 7;
        int hy = pi / 34, hx = pi - hy * 34;
        int gy = by * 4 + hy - 1, gx = bx * 32 + hx - 1;
        uint4 v = {0u, 0u, 0u, 0u};
        if (gy >= 0 && gy < Hh && gx >= 0 && gx < Ww)
            v = *(const uint4*)(emb + (((size_t)(b * Hh + gy)) * Ww + gx) * EMB + e8 * 8);
        *(uint4*)(&Es[pi * SP + e8 * 8]) = v;
    }
    for (int ci = tid; ci < 2304; ci += 256) {
        int n = ci / 72, k8 = ci - n * 72;
        *(uint4*)(&Bs[n * SB + k8 * 8]) = *(const uint4*)(wT + n * 576 + k8 * 8);
    }
    __syncthreads();

    int wid = tid >> 6, lane = tid & 63;
    int lr = lane & 15, hi = lane >> 4, lk = hi * 8;

    floatx4 acc[2][2];
    #pragma unroll
    for (int mi = 0; mi < 2; ++mi)
        #pragma unroll
        for (int ni = 0; ni < 2; ++ni)
            acc[mi][ni] = (floatx4){0.f, 0.f, 0.f, 0.f};

    #pragma unroll
    for (int tap = 0; tap < 9; ++tap) {
        int dy = tap / 3, dx = tap - dy * 3;
        #pragma unroll
        for (int ks = 0; ks < 2; ++ks) {
            short8 a[2], bb[2];
            #pragma unroll
            for (int mi = 0; mi < 2; ++mi) {
                int p = wid * 32 + mi * 16 + lr;
                int r = p >> 5, c = p & 31;
                a[mi] = *(const short8*)(&Es[((r + dy) * 34 + (c + dx)) * SP + ks * 32 + lk]);
            }
            #pragma unroll
            for (int ni = 0; ni < 2; ++ni)
                bb[ni] = *(const short8*)(&Bs[(ni * 16 + lr) * SB + tap * 64 + ks * 32 + lk]);
            #pragma unroll
            for (int mi = 0; mi < 2; ++mi)
                #pragma unroll
                for (int ni = 0; ni < 2; ++ni)
                    acc[mi][ni] = __builtin_amdgcn_mfma_f32_16x16x32_bf16(a[mi], bb[ni], acc[mi][ni], 0, 0, 0);
        }
    }

    #pragma unroll
    for (int mi = 0; mi < 2; ++mi) {
        #pragma unroll
        for (int ni = 0; ni < 2; ++ni) {
            int n = ni * 16 + lr;
            if (n < KK) {
                float bs = bias[n];
                #pragma unroll
                for (int j = 0; j < 4; ++j) {
                    int p = wid * 32 + mi * 16 + hi * 4 + j;
                    int r = p >> 5, c = p & 31;
                    size_t gq = ((size_t)(b * Hh + by * 4 + r)) * Ww + bx * 32 + c;
                    y[gq * KK + n] = acc[mi][ni][j] + bs;
                }
            }
        }
    }
}

// ================ fused carafe + gate + final double-GEMM + blend ================
// One block = 4x4 coarse tile = 64 fine pixels = one M=64 GEMM tile.
// FAITHFUL gather: out ch c, tap j reads flat elem i=c*25+j of the per-pixel
// [pos][ch] vector: pos p=i>>7, ch=i&127 (channel mixing!). With the 8x8 staged
// region, value = patches[((ry+p/5)*8 + rx+p%5)*128 + ch] = cpbase + offs[j],
// offs precomputed per thread (fixed c). FMA order j=0..24 == proven kernel.
// LDS: [0,32768) patches f32 (8x8 px x 128ch) -> overlaid by Ws after gather
//      [32768,40960) wsm (64 fine px x 32 f32) -> dead before Ws overlay
//      [40960,41216) g_lds (16 gates)          -> survives (beyond Ws end 34816)
//      [41216,58624) Xs (64x136 bf16)
#define LDSP 136
__global__ __launch_bounds__(256) void carafe_final_kernel(
        const float* __restrict__ coarse,   // [B,64,64,128]
        const float* __restrict__ f_conv,   // [B,128,128,25]
        const float* __restrict__ c_conv,   // [B,64,64,25]
        const float* __restrict__ w_gate,   // [128]
        const float* __restrict__ b_gate,   // [1]
        const unsigned short* __restrict__ WcT,  // bf16 [o][k]
        const unsigned short* __restrict__ WfT,  // bf16 [p][o]
        const float* __restrict__ b_coarse,
        const float* __restrict__ b_fineout,
        float* __restrict__ out) {
    __shared__ __align__(16) char smem[58624];
    float* patches = (float*)smem;                        // [64][128]
    float* wsm     = (float*)(smem + 32768);              // [64][32]
    float* g_lds   = (float*)(smem + 40960);              // [16]
    unsigned short* Ws = (unsigned short*)smem;           // [128][LDSP] overlay
    unsigned short* Xs = (unsigned short*)(smem + 41216); // [64][LDSP]

    const int h = 64, w = 64, H2 = 128, W2 = 128;
    int tid = threadIdx.x;
    int blk = blockIdx.x;
    int cx0 = (blk & 15) * 4;
    int cy0 = ((blk >> 4) & 15) * 4;
    int b = blk >> 8;

    // ---- Phase A: stage 8x8 coarse halo region (f32), 2048 float4 ----
    for (int ci = tid; ci < 2048; ci += 256) {
        int pi = ci >> 5;                 // staged pixel 0..63
        int c4 = (ci & 31) << 2;
        int sy = cy0 - 2 + (pi >> 3);
        int sx = cx0 - 2 + (pi & 7);
        float4 v = {0.f, 0.f, 0.f, 0.f};
        if (sy >= 0 && sy < h && sx >= 0 && sx < w)
            v = *(const float4*)(coarse + (((size_t)(b * h + sy)) * w + sx) * CC + c4);
        *(float4*)(&patches[pi * 128 + c4]) = v;
    }

    // ---- Phase B: softmax for 64 fine pixels (wave-parallel, 2 px per pass) ----
    int wid = tid >> 6, lane = tid & 63;
    {
        int k = lane & 31;
        #pragma unroll
        for (int pass = 0; pass < 8; ++pass) {
            int fp = wid * 16 + pass * 2 + (lane >> 5);
            int fry = fp >> 3, frx = fp & 7;
            int fy = 2 * cy0 + fry, fx = 2 * cx0 + frx;
            int cy = cy0 + (fry >> 1), cx = cx0 + (frx >> 1);
            size_t fq = ((size_t)(b * H2 + fy)) * W2 + fx;
            size_t cq = ((size_t)(b * h + cy)) * w + cx;
            float v = -1e30f;
            if (k < KK)
                v = f_conv[fq * KK + k] + c_conv[cq * KK + k];
            float m = v;
            #pragma unroll
            for (int mask = 16; mask > 0; mask >>= 1)
                m = fmaxf(m, __shfl_xor(m, mask, 32));
            float e = (k < KK) ? __expf(v - m) : 0.0f;
            float s = e;
            #pragma unroll
            for (int mask = 16; mask > 0; mask >>= 1)
                s += __shfl_xor(s, mask, 32);
            wsm[fp * 32 + k] = e / s;
        }
    }
    __syncthreads();

    // ---- gate for the 16 owned coarse pixels (from staged centers) ----
    {
        int cp = tid >> 4;        // 0..15
        int part = tid & 15;
        int pidx = ((cp >> 2) + 2) * 8 + (cp & 3) + 2;   // staged center
        const float* pc = patches + pidx * 128 + part * 8;
        float4 a0 = *(const float4*)(pc);
        float4 a1 = *(const float4*)(pc + 4);
        float4 g0 = *(const float4*)(w_gate + part * 8);
        float4 g1 = *(const float4*)(w_gate + part * 8 + 4);
        float acc = a0.x * g0.x + a0.y * g0.y + a0.z * g0.z + a0.w * g0.w
                  + a1.x * g1.x + a1.y * g1.y + a1.z * g1.z + a1.w * g1.w;
        #pragma unroll
        for (int mask = 8; mask > 0; mask >>= 1)
            acc += __shfl_xor(acc, mask, 16);
        if (part == 0) {
            float z = acc + b_gate[0];
            g_lds[cp] = 1.0f / (1.0f + __expf(-z));
        }
    }

    // ---- Phase C: FAITHFUL gather -> Xs (bf16) ----
    {
        int ph = tid >> 7;          // fine-row parity within coarse parent
        int c  = tid & 127;         // output channel
        // per-c flat offsets (fixed across the 16 coarse pixels)
        int offs[KK];
        int c25 = c * 25;
        #pragma unroll
        for (int j = 0; j < KK; ++j) {
            int i = c25 + j;
            int p = i >> 7;             // patch position 0..24
            int ch = i & 127;           // mixed channel
            int pd = (p * 205) >> 10;   // p/5
            int pm = p - pd * 5;
            offs[j] = (pd * 8 + pm) * 128 + ch;
        }
        for (int cp = 0; cp < 16; ++cp) {
            int ry = cp >> 2, rx = cp & 3;
            int cpbase = (ry * 8 + rx) * 128;
            int fpA = (2 * ry + ph) * 8 + 2 * rx;
            float w0[28], w1[28];
            #pragma unroll
            for (int j4 = 0; j4 < 7; ++j4) {
                *(float4*)(&w0[j4 * 4]) = *(const float4*)(&wsm[fpA * 32 + j4 * 4]);
                *(float4*)(&w1[j4 * 4]) = *(const float4*)(&wsm[(fpA + 1) * 32 + j4 * 4]);
            }
            float acc0 = 0.0f, acc1 = 0.0f;
            #pragma unroll
            for (int j = 0; j < KK; ++j) {
                float pv = patches[cpbase + offs[j]];
                acc0 += w0[j] * pv;
                acc1 += w1[j] * pv;
            }
            Xs[fpA * LDSP + c] = f32_to_bf16(acc0);
            Xs[(fpA + 1) * LDSP + c] = f32_to_bf16(acc1);
        }
    }
    __syncthreads();     // gather done; patches/wsm dead

    // ---- stage Ws = WcT (overlays patches) ----
    {
        const uint4* wsrc = (const uint4*)WcT;
        for (int ci = tid; ci < 2048; ci += 256) {
            int r = ci >> 4, c = ci & 15;
            *(uint4*)(&Ws[r * LDSP + c * 8]) = wsrc[ci];
        }
    }
    __syncthreads();

    int wm = wid >> 1, wn = wid & 1;
    int lr = lane & 15;
    int lk = (lane >> 4) * 8;
    int lrow4 = (lane >> 4) * 4;

    floatx4 acc1[2][4];
    #pragma unroll
    for (int mi = 0; mi < 2; ++mi)
        #pragma unroll
        for (int ni = 0; ni < 4; ++ni)
            acc1[mi][ni] = (floatx4){0.f, 0.f, 0.f, 0.f};

    #pragma unroll
    for (int kk = 0; kk < 128; kk += 32) {
        short8 a[2], bb[4];
        #pragma unroll
        for (int mi = 0; mi < 2; ++mi)
            a[mi] = *(const short8*)(&Xs[(wm * 32 + mi * 16 + lr) * LDSP + kk + lk]);
        #pragma unroll
        for (int ni = 0; ni < 4; ++ni)
            bb[ni] = *(const short8*)(&Ws[(wn * 64 + ni * 16 + lr) * LDSP + kk + lk]);
        #pragma unroll
        for (int mi = 0; mi < 2; ++mi)
            #pragma unroll
            for (int ni = 0; ni < 4; ++ni)
                acc1[mi][ni] = __builtin_amdgcn_mfma_f32_16x16x32_bf16(a[mi], bb[ni], acc1[mi][ni], 0, 0, 0);
    }
    __syncthreads();     // GEMM1 done reading Ws & Xs

    {
        const uint4* wsrc = (const uint4*)WfT;
        for (int ci = tid; ci < 2048; ci += 256) {
            int r = ci >> 4, c = ci & 15;
            *(uint4*)(&Ws[r * LDSP + c * 8]) = wsrc[ci];
        }
    }
    #pragma unroll
    for (int mi = 0; mi < 2; ++mi) {
        #pragma unroll
        for (int ni = 0; ni < 4; ++ni) {
            int col = wn * 64 + ni * 16 + lr;
            float bc = b_coarse[col];
            #pragma unroll
            for (int j = 0; j < 4; ++j) {
                int row = wm * 32 + mi * 16 + lrow4 + j;
                float v = acc1[mi][ni][j] + bc;
                acc1[mi][ni][j] = v;
                Xs[row * LDSP + col] = f32_to_bf16(v);
            }
        }
    }
    __syncthreads();

    floatx4 acc2[2][4];
    #pragma unroll
    for (int mi = 0; mi < 2; ++mi)
        #pragma unroll
        for (int ni = 0; ni < 4; ++ni)
            acc2[mi][ni] = (floatx4){0.f, 0.f, 0.f, 0.f};

    #pragma unroll
    for (int kk = 0; kk < 128; kk += 32) {
        short8 a[2], bb[4];
        #pragma unroll
        for (int mi = 0; mi < 2; ++mi)
            a[mi] = *(const short8*)(&Xs[(wm * 32 + mi * 16 + lr) * LDSP + kk + lk]);
        #pragma unroll
        for (int ni = 0; ni < 4; ++ni)
            bb[ni] = *(const short8*)(&Ws[(wn * 64 + ni * 16 + lr) * LDSP + kk + lk]);
        #pragma unroll
        for (int mi = 0; mi < 2; ++mi)
            #pragma unroll
            for (int ni = 0; ni < 4; ++ni)
                acc2[mi][ni] = __builtin_amdgcn_mfma_f32_16x16x32_bf16(a[mi], bb[ni], acc2[mi][ni], 0, 0, 0);
    }

    // ---- epilogue: blend with gate, scatter to global ----
    #pragma unroll
    for (int mi = 0; mi < 2; ++mi) {
        #pragma unroll
        for (int ni = 0; ni < 4; ++ni) {
            int col = wn * 64 + ni * 16 + lr;
            float bf = b_fineout[col];
            #pragma unroll
            for (int j = 0; j < 4; ++j) {
                int row = wm * 32 + mi * 16 + lrow4 + j;   // local fine pixel
                int fry = row >> 3, frx = row & 7;
                float g = g_lds[((fry >> 1) << 2) + (frx >> 1)];
                int fy = 2 * cy0 + fry, fx = 2 * cx0 + frx;
                size_t q = ((size_t)(b * H2 + fy)) * W2 + fx;
                float co = acc1[mi][ni][j];
                float fo = acc2[mi][ni][j] + bf;
                out[q * FILTERS + col] = g * fo + (1.0f - g) * co;
            }
        }
    }
}

extern "C" void kernel_launch(void* const* d_in, const int* in_sizes, int n_in,
                              void* d_out, int out_size, void* d_ws, size_t ws_size,
                              hipStream_t stream) {
    const float* fine      = (const float*)d_in[0];
    const float* coarse    = (const float*)d_in[1];
    const float* w_gate    = (const float*)d_in[2];
    const float* b_gate    = (const float*)d_in[3];
    const float* w_sfine   = (const float*)d_in[4];
    const float* w_scoarse = (const float*)d_in[5];
    const float* b_scoarse = (const float*)d_in[6];
    const float* w_content = (const float*)d_in[7];
    const float* b_content = (const float*)d_in[8];
    const float* w_coarse  = (const float*)d_in[9];
    const float* b_coarse  = (const float*)d_in[10];
    const float* w_fineout = (const float*)d_in[11];
    const float* b_fineout = (const float*)d_in[12];
    float* out = (float*)d_out;

    const int B = 2, H = 128, W = 128, h = 64, w = 64;
    const int MF = B * H * W;   // 32768
    const int MC = B * h * w;   // 8192

    char* ws = (char*)d_ws;
    size_t off = 0;
    auto alloc = [&](size_t bytes) {
        void* p = ws + off;
        off = (off + bytes + 255) & ~(size_t)255;
        return p;
    };
    unsigned short* f_emb    = (unsigned short*)alloc((size_t)MF * EMB * 2);
    unsigned short* c_emb    = (unsigned short*)alloc((size_t)MC * EMB * 2);
    float* f_conv            = (float*)alloc((size_t)MF * KK * 4);
    float* c_conv            = (float*)alloc((size_t)MC * KK * 4);
    unsigned short* wconT    = (unsigned short*)alloc(32 * 576 * 2);
    unsigned short* wcT      = (unsigned short*)alloc(128 * 128 * 2);
    unsigned short* wfT      = (unsigned short*)alloc(128 * 128 * 2);

    const int NEF = MF / 128;         // 256 fine embed blocks
    const int NEC = MC / 128;         // 64 coarse embed blocks
    const int NEB = NEF + NEC;        // 320 embed blocks
    const int NWT = 200;              // 51200 transpose elems / 256
    const int NCF = B * (H / 4) * (W / 32);   // 256 fine content blocks
    const int NCC = B * (h / 4) * (w / 32);   // 64 coarse content blocks

    embed_both_kernel<<<NEB + NWT, 256, 0, stream>>>(fine, w_sfine, coarse, w_scoarse, b_scoarse,
                                                     f_emb, c_emb, NEF, NEB,
                                                     w_content, w_coarse, w_fineout,
                                                     wconT, wcT, wfT);
    content_both_kernel<<<NCF + NCC, 256, 0, stream>>>(f_emb, c_emb, wconT, b_content,
                                                       f_conv, c_conv, NCF);
    carafe_final_kernel<<<B * 16 * 16, 256, 0, stream>>>(coarse, f_conv, c_conv, w_gate, b_gate,
                                                         wcT, wfT, b_coarse, b_fineout, out);
}